// Round 22
// baseline (26.981 us; speedup 1.0000x reference)
//
#include <hip/hip_runtime.h>
#include <hip/hip_bf16.h>
#include <math.h>

#define T_DIM 32
#define B_DIM 128
#define D_DIM 512
#define M_DIM 1024

constexpr float DT = 0.1875f;          // 3.0 / 16
constexpr float INV_2PI = 0.15915494309189535f;

typedef __attribute__((ext_vector_type(8)))  short bf16x8;   // MFMA A/B operand
typedef __attribute__((ext_vector_type(16))) float f32x16;   // 32x32 MFMA acc
typedef __attribute__((ext_vector_type(2)))  float f32x2;    // packed (cos,sin)

__device__ __forceinline__ ushort f2bf(float f) {            // RNE fp32->bf16
    unsigned u = __float_as_uint(f);
    u += 0x7FFFu + ((u >> 16) & 1u);
    return (ushort)(u >> 16);
}

// async global->LDS, 16B per lane; LDS dest is wave-uniform base + lane*16.
__device__ __forceinline__ void gload16(const void* g, void* l) {
    __builtin_amdgcn_global_load_lds(
        (const __attribute__((address_space(1))) void*)g,
        (__attribute__((address_space(3))) void*)l, 16, 0, 0);
}

// v_sin/v_cos take REVOLUTIONS (ISA: D=sin(S0*2pi)); reduce with floor.
__device__ __forceinline__ void fast_sincos(float theta, float& s, float& c) {
    float r = theta * INV_2PI;
    r -= floorf(r);
    s = __builtin_amdgcn_sinf(r);
    c = __builtin_amdgcn_cosf(r);
}

// ---------- K1: prep (validated R8-R21). blocks 0..63: colnorm+transpose -> ant.
//                blocks 64..575: z -> bf16. ----------
__global__ __launch_bounds__(256) void prep_kernel(const float* __restrict__ A,
                                                   const float* __restrict__ z,
                                                   ushort* __restrict__ zb,
                                                   ushort* __restrict__ ant) {
    const int bid = blockIdx.x;
    const int tid = threadIdx.x;

    if (bid >= 64) {                       // ---- zconv: 512 blocks x 4096 floats ----
        const size_t base = (size_t)(bid - 64) * 4096 + tid * 8;
#pragma unroll
        for (int j = 0; j < 2; ++j) {
            const size_t i = base + j * 2048;
            const float4 a = *reinterpret_cast<const float4*>(&z[i]);
            const float4 b = *reinterpret_cast<const float4*>(&z[i + 4]);
            uint4 p;
            p.x = (unsigned)f2bf(a.x) | ((unsigned)f2bf(a.y) << 16);
            p.y = (unsigned)f2bf(a.z) | ((unsigned)f2bf(a.w) << 16);
            p.z = (unsigned)f2bf(b.x) | ((unsigned)f2bf(b.y) << 16);
            p.w = (unsigned)f2bf(b.z) | ((unsigned)f2bf(b.w) << 16);
            *reinterpret_cast<uint4*>(&zb[i]) = p;
        }
        return;
    }

    __shared__ float red[256];
    __shared__ float inv[16];
    __shared__ float tile[128][17];

    const int mB = bid * 16;
    const int mo = tid & 15;
    const int dg = tid >> 4;
    float ss = 0.0f;
#pragma unroll 4
    for (int i = 0; i < 32; ++i) {
        const float v = A[(size_t)(dg * 32 + i) * M_DIM + mB + mo];
        ss = fmaf(v, v, ss);
    }
    red[tid] = ss;
    __syncthreads();
    for (int s = 128; s >= 16; s >>= 1) {
        if (tid < s) red[tid] += red[tid + s];
        __syncthreads();
    }
    if (tid < 16) inv[tid] = 1.0f / fmaxf(sqrtf(red[tid]), 1e-12f);

#pragma unroll
    for (int ch = 0; ch < 4; ++ch) {
        const int dB = ch * 128;
#pragma unroll
        for (int q = 0; q < 2; ++q) {
            const int s  = tid + 256 * q;
            const int r  = s >> 2;
            const int c4 = (s & 3) * 4;
            const float4 v = *reinterpret_cast<const float4*>(
                &A[(size_t)(dB + r) * M_DIM + mB + c4]);
            tile[r][c4]     = v.x;
            tile[r][c4 + 1] = v.y;
            tile[r][c4 + 2] = v.z;
            tile[r][c4 + 3] = v.w;
        }
        __syncthreads();
        {
            const int m  = tid >> 4;
            const int d8 = (tid & 15) * 8;
            const float sc = inv[m];
            uint4 p;
            p.x = (unsigned)f2bf(tile[d8 + 0][m] * sc) | ((unsigned)f2bf(tile[d8 + 1][m] * sc) << 16);
            p.y = (unsigned)f2bf(tile[d8 + 2][m] * sc) | ((unsigned)f2bf(tile[d8 + 3][m] * sc) << 16);
            p.z = (unsigned)f2bf(tile[d8 + 4][m] * sc) | ((unsigned)f2bf(tile[d8 + 5][m] * sc) << 16);
            p.w = (unsigned)f2bf(tile[d8 + 6][m] * sc) | ((unsigned)f2bf(tile[d8 + 7][m] * sc) << 16);
            *reinterpret_cast<uint4*>(&ant[(size_t)(mB + m) * D_DIM + dB + d8]) = p;
        }
        __syncthreads();
    }
}

// ---------- K2: fused GEMM+CF with 32x32x16 MFMA ----------
// Tile 128b x 128m, 8 waves (2 wr x 4 wc), wave = 64b x 32m = 2 stacked 32x32 tiles.
// Grid 256 XCD-grouped (8 blocks/t-slice: zb L2 re-reads halved vs R21).
// 32x32x16 halves LDS fragment bytes per output. C-layout (guide-verified):
// col = lane&31, row = (reg&3) + 8*(reg>>2) + 4*(lane>>5) -> each lane's 32 acc
// values share one m-col and bijectively cover the wave's 64 b-rows.
#define CHEB(CS) { const f32x2 nxt = c2 * cur - prev; prev = cur; cur = nxt; CS += cur; }
#define CF_ALL(V) { \
    float s1, c1; fast_sincos((V) * DT, s1, c1); \
    const float c2 = 2.0f * c1; \
    f32x2 prev = {1.0f, 0.0f}; \
    f32x2 cur  = {c1, s1}; \
    cs0 += cur; \
    CHEB(cs1)  CHEB(cs2)  CHEB(cs3)  CHEB(cs4)  CHEB(cs5) \
    CHEB(cs6)  CHEB(cs7)  CHEB(cs8)  CHEB(cs9)  CHEB(cs10) \
    CHEB(cs11) CHEB(cs12) CHEB(cs13) CHEB(cs14) CHEB(cs15) }
#define RED32(CS) { CS.x += __shfl_xor(CS.x, 32); CS.y += __shfl_xor(CS.y, 32); }
#define ST(CS, K) { wred[wc][l31][K] = CS.x; wred[wc][l31][16 + K] = CS.y; }
#define FIN(CS, KK) { \
    constexpr float tk = DT * (float)(KK); \
    const float g  = __expf(-0.5f * tk * tk); \
    const float w  = (((KK) == 16) ? DT : 2.0f * DT) * g; \
    const float totC = wred[wc][l31][(KK) - 1]      + CS.x; \
    const float totS = wred[wc][l31][16 + (KK) - 1] + CS.y; \
    const float cm = fmaf(totC, invB, -g); \
    const float sm = totS * invB; \
    s = fmaf(w, fmaf(cm, cm, sm * sm), s); }

__global__ __launch_bounds__(512) void fused_kernel(const ushort* __restrict__ zb,
                                                    const ushort* __restrict__ ant,
                                                    float* __restrict__ partials) {
    // As (32 KB) unioned with CF-reduce scratch (wred 16.9 KB, used after final barrier).
    // Total LDS = 32K + 32K = 64 KB -> 2 blocks/CU, 16 waves/CU.
    __shared__ __align__(16) union SharedU {
        ushort As[128 * 128];
        struct { float wred[4][32][33]; float bred[4]; } r;
    } u;
    __shared__ __align__(16) ushort Bs[128 * 128];

    const int tid = threadIdx.x;
    // XCD-grouped bijection: grid 256; xcd = bid&7 owns t in {xcd*4..xcd*4+3} x 8 m-blocks.
    const int bid  = blockIdx.x;                    // 0..255
    const int idx  = bid >> 3;                      // 0..31
    const int t    = (bid & 7) * 4 + (idx & 3);
    const int mBi  = idx >> 2;                      // 0..7
    const int mB   = mBi * 128;

    const int wave = tid >> 6;                      // 0..7
    const int lane = tid & 63;
    const int wr   = wave >> 2;                     // 0..1  b-row half (64 rows)
    const int wc   = wave & 3;                      // 0..3  m-col quarter (32 cols)
    const int l31  = lane & 31;
    const int lh5  = lane >> 5;                     // 0..1 (k-half of 16-k step)

    const int rofs = lane >> 4;                     // 0..3 (staging row offset)
    const int gl   = lane & 15;                     // staging granule lane

    const ushort* zrow = zb + (size_t)t * B_DIM * D_DIM;

    f32x16 acc[2];
    acc[0] = (f32x16)(0.0f);
    acc[1] = (f32x16)(0.0f);

#pragma unroll
    for (int it = 0; it < 4; ++it) {
        const int k0 = it * 128;
        // stage A (128 rows) + B (128 m-rows): 4 gload16 each per wave; pre-swizzled src
#pragma unroll
        for (int j = 0; j < 4; ++j) {
            const int r0  = wave * 16 + j * 4;
            const int row = r0 + rofs;
            const int gs  = gl ^ (row & 15);
            gload16(&zrow[(size_t)row * D_DIM + k0 + gs * 8], &u.As[r0 * 128]);
        }
#pragma unroll
        for (int j = 0; j < 4; ++j) {
            const int r0  = wave * 16 + j * 4;
            const int row = r0 + rofs;
            const int gs  = gl ^ (row & 15);
            gload16(&ant[(size_t)(mB + row) * D_DIM + k0 + gs * 8], &Bs[r0 * 128]);
        }
        __syncthreads();                   // drains vmcnt -> LDS visible

#pragma unroll
        for (int ks = 0; ks < 8; ++ks) {   // 8 k-steps of 16
            const int brow = wc * 32 + l31;
            const int bco  = ((ks * 2 + lh5) ^ (brow & 15)) * 8;
            const bf16x8 bfrag = *reinterpret_cast<const bf16x8*>(&Bs[brow * 128 + bco]);
#pragma unroll
            for (int bt = 0; bt < 2; ++bt) {
                const int arow = wr * 64 + bt * 32 + l31;
                const int aco  = ((ks * 2 + lh5) ^ (arow & 15)) * 8;
                const bf16x8 afrag = *reinterpret_cast<const bf16x8*>(&u.As[arow * 128 + aco]);
                acc[bt] = __builtin_amdgcn_mfma_f32_32x32x16_bf16(afrag, bfrag, acc[bt], 0, 0, 0);
            }
        }
        __syncthreads();                   // readers done before overwrite / union reuse
    }

    float (&wred)[4][32][33] = u.r.wred;   // As region dead past final barrier
    float (&bred)[4] = u.r.bred;

    // ---- CF: lane's col m = mB + wc*32 + l31; 32 acc values = its wave's 64 b-rows
    //      (after xor-32 fold: lanes l and l+32 hold row-groups offset by 4) ----
    f32x2 cs0  = {0.f, 0.f}, cs1  = {0.f, 0.f}, cs2  = {0.f, 0.f}, cs3  = {0.f, 0.f};
    f32x2 cs4  = {0.f, 0.f}, cs5  = {0.f, 0.f}, cs6  = {0.f, 0.f}, cs7  = {0.f, 0.f};
    f32x2 cs8  = {0.f, 0.f}, cs9  = {0.f, 0.f}, cs10 = {0.f, 0.f}, cs11 = {0.f, 0.f};
    f32x2 cs12 = {0.f, 0.f}, cs13 = {0.f, 0.f}, cs14 = {0.f, 0.f}, cs15 = {0.f, 0.f};

#pragma unroll
    for (int bt = 0; bt < 2; ++bt) {
        const f32x16 av = acc[bt];
#pragma unroll
        for (int r = 0; r < 16; ++r) {
            CF_ALL(av[r])
        }
    }

    // fold the two lane-halves (rows +0/+4 groups): after this, value = sum over 64 b
    RED32(cs0)  RED32(cs1)  RED32(cs2)  RED32(cs3)
    RED32(cs4)  RED32(cs5)  RED32(cs6)  RED32(cs7)
    RED32(cs8)  RED32(cs9)  RED32(cs10) RED32(cs11)
    RED32(cs12) RED32(cs13) RED32(cs14) RED32(cs15)

    if (wr == 0 && lane < 32) {            // waves 0..3 store their b-half sums
        ST(cs0, 0)   ST(cs1, 1)   ST(cs2, 2)   ST(cs3, 3)
        ST(cs4, 4)   ST(cs5, 5)   ST(cs6, 6)   ST(cs7, 7)
        ST(cs8, 8)   ST(cs9, 9)   ST(cs10, 10) ST(cs11, 11)
        ST(cs12, 12) ST(cs13, 13) ST(cs14, 14) ST(cs15, 15)
    }
    __syncthreads();

    float s = 0.0f;
    if (wr == 1) {                         // waves 4..7: combine halves, finish stat
        const float invB = 1.0f / 128.0f;
        FIN(cs0, 1)   FIN(cs1, 2)   FIN(cs2, 3)   FIN(cs3, 4)
        FIN(cs4, 5)   FIN(cs5, 6)   FIN(cs6, 7)   FIN(cs7, 8)
        FIN(cs8, 9)   FIN(cs9, 10)  FIN(cs10, 11) FIN(cs11, 12)
        FIN(cs12, 13) FIN(cs13, 14) FIN(cs14, 15) FIN(cs15, 16)
        // butterfly over 64 lanes: each of the 32 cols counted 2x (lane-half dup)
#pragma unroll
        for (int m = 1; m < 64; m <<= 1) s += __shfl_xor(s, m);
        if (lane == 0) bred[wc] = s;
    }
    __syncthreads();
    // plain uncontended store (R17); dup factor 2 folded into finalize scale
    if (tid == 0)
        partials[t * 8 + mBi] = bred[0] + bred[1] + bred[2] + bred[3];
}

// ---------- K3: final reduce of 256 partials ----------
// out = sum(partials) * (0.5 dup) * 128 / (T*M) = sum / 512
__global__ __launch_bounds__(256) void finalize_kernel(const float* __restrict__ partials,
                                                       float* __restrict__ out) {
    __shared__ float red[256];
    const int tid = threadIdx.x;
    red[tid] = partials[tid];
    __syncthreads();
    for (int s = 128; s > 0; s >>= 1) {
        if (tid < s) red[tid] += red[tid + s];
        __syncthreads();
    }
    if (tid == 0) out[0] = red[0] * (1.0f / 512.0f);
}

extern "C" void kernel_launch(void* const* d_in, const int* in_sizes, int n_in,
                              void* d_out, int out_size, void* d_ws, size_t ws_size,
                              hipStream_t stream) {
    const float* z = (const float*)d_in[0];   // (32,128,512)
    const float* A = (const float*)d_in[1];   // (512,1024)
    float* out = (float*)d_out;

    char* ws = (char*)d_ws;
    ushort* zb       = (ushort*)ws;                        // 4 MB
    ushort* ant      = (ushort*)(ws + 4 * 1024 * 1024);    // 1 MB
    float*  partials = (float*)(ws + 5 * 1024 * 1024);     // 1 KB

    prep_kernel<<<576, 256, 0, stream>>>(A, z, zb, ant);
    fused_kernel<<<256, 512, 0, stream>>>(zb, ant, partials);
    finalize_kernel<<<1, 256, 0, stream>>>(partials, out);
}

// Round 23
// 26.649 us; speedup vs baseline: 1.0125x; 1.0125x over previous
//
#include <hip/hip_runtime.h>
#include <hip/hip_bf16.h>
#include <math.h>

#define T_DIM 32
#define B_DIM 128
#define D_DIM 512
#define M_DIM 1024

constexpr float DT = 0.1875f;          // 3.0 / 16
constexpr float INV_2PI = 0.15915494309189535f;

typedef __attribute__((ext_vector_type(8))) short bf16x8;   // 8 bf16 = 4 VGPR
typedef __attribute__((ext_vector_type(4))) float f32x4;    // MFMA acc
typedef __attribute__((ext_vector_type(2))) float f32x2;    // packed (cos,sin)

__device__ __forceinline__ ushort f2bf(float f) {           // RNE fp32->bf16
    unsigned u = __float_as_uint(f);
    u += 0x7FFFu + ((u >> 16) & 1u);
    return (ushort)(u >> 16);
}

// async global->LDS, 16B per lane; LDS dest is wave-uniform base + lane*16.
__device__ __forceinline__ void gload16(const void* g, void* l) {
    __builtin_amdgcn_global_load_lds(
        (const __attribute__((address_space(1))) void*)g,
        (__attribute__((address_space(3))) void*)l, 16, 0, 0);
}

// v_sin/v_cos take REVOLUTIONS (ISA: D=sin(S0*2pi)); reduce with floor.
__device__ __forceinline__ void fast_sincos(float theta, float& s, float& c) {
    float r = theta * INV_2PI;
    r -= floorf(r);
    s = __builtin_amdgcn_sinf(r);
    c = __builtin_amdgcn_cosf(r);
}

// ---------- K1: prep (validated R8-R21). blocks 0..63: colnorm+transpose -> ant.
//                blocks 64..575: z -> bf16. ----------
__global__ __launch_bounds__(256) void prep_kernel(const float* __restrict__ A,
                                                   const float* __restrict__ z,
                                                   ushort* __restrict__ zb,
                                                   ushort* __restrict__ ant) {
    const int bid = blockIdx.x;
    const int tid = threadIdx.x;

    if (bid >= 64) {                       // ---- zconv: 512 blocks x 4096 floats ----
        const size_t base = (size_t)(bid - 64) * 4096 + tid * 8;
#pragma unroll
        for (int j = 0; j < 2; ++j) {
            const size_t i = base + j * 2048;
            const float4 a = *reinterpret_cast<const float4*>(&z[i]);
            const float4 b = *reinterpret_cast<const float4*>(&z[i + 4]);
            uint4 p;
            p.x = (unsigned)f2bf(a.x) | ((unsigned)f2bf(a.y) << 16);
            p.y = (unsigned)f2bf(a.z) | ((unsigned)f2bf(a.w) << 16);
            p.z = (unsigned)f2bf(b.x) | ((unsigned)f2bf(b.y) << 16);
            p.w = (unsigned)f2bf(b.z) | ((unsigned)f2bf(b.w) << 16);
            *reinterpret_cast<uint4*>(&zb[i]) = p;
        }
        return;
    }

    __shared__ float red[256];
    __shared__ float inv[16];
    __shared__ float tile[128][17];

    const int mB = bid * 16;
    const int mo = tid & 15;
    const int dg = tid >> 4;
    float ss = 0.0f;
#pragma unroll 4
    for (int i = 0; i < 32; ++i) {
        const float v = A[(size_t)(dg * 32 + i) * M_DIM + mB + mo];
        ss = fmaf(v, v, ss);
    }
    red[tid] = ss;
    __syncthreads();
    for (int s = 128; s >= 16; s >>= 1) {
        if (tid < s) red[tid] += red[tid + s];
        __syncthreads();
    }
    if (tid < 16) inv[tid] = 1.0f / fmaxf(sqrtf(red[tid]), 1e-12f);

#pragma unroll
    for (int ch = 0; ch < 4; ++ch) {
        const int dB = ch * 128;
#pragma unroll
        for (int q = 0; q < 2; ++q) {
            const int s  = tid + 256 * q;
            const int r  = s >> 2;
            const int c4 = (s & 3) * 4;
            const float4 v = *reinterpret_cast<const float4*>(
                &A[(size_t)(dB + r) * M_DIM + mB + c4]);
            tile[r][c4]     = v.x;
            tile[r][c4 + 1] = v.y;
            tile[r][c4 + 2] = v.z;
            tile[r][c4 + 3] = v.w;
        }
        __syncthreads();
        {
            const int m  = tid >> 4;
            const int d8 = (tid & 15) * 8;
            const float sc = inv[m];
            uint4 p;
            p.x = (unsigned)f2bf(tile[d8 + 0][m] * sc) | ((unsigned)f2bf(tile[d8 + 1][m] * sc) << 16);
            p.y = (unsigned)f2bf(tile[d8 + 2][m] * sc) | ((unsigned)f2bf(tile[d8 + 3][m] * sc) << 16);
            p.z = (unsigned)f2bf(tile[d8 + 4][m] * sc) | ((unsigned)f2bf(tile[d8 + 5][m] * sc) << 16);
            p.w = (unsigned)f2bf(tile[d8 + 6][m] * sc) | ((unsigned)f2bf(tile[d8 + 7][m] * sc) << 16);
            *reinterpret_cast<uint4*>(&ant[(size_t)(mB + m) * D_DIM + dB + d8]) = p;
        }
        __syncthreads();
    }
}

// ---------- K2: fused GEMM+CF (R19 structure) + XCD-grouped mapping (R21 best) ----------
// 1D grid 512; xcd=bid&7 owns 4 whole t-slices x 16 m-blocks -> each zb t-slice
// cached in exactly one XCD L2. Pure bijective remap. [R21 measured: 26.8 us total]
#define CHEB(CS) { const f32x2 nxt = c2 * cur - prev; prev = cur; cur = nxt; CS += cur; }
#define CF_ALL(V) { \
    float s1, c1; fast_sincos((V) * DT, s1, c1); \
    const float c2 = 2.0f * c1; \
    f32x2 prev = {1.0f, 0.0f}; \
    f32x2 cur  = {c1, s1}; \
    cs0 += cur; \
    CHEB(cs1)  CHEB(cs2)  CHEB(cs3)  CHEB(cs4)  CHEB(cs5) \
    CHEB(cs6)  CHEB(cs7)  CHEB(cs8)  CHEB(cs9)  CHEB(cs10) \
    CHEB(cs11) CHEB(cs12) CHEB(cs13) CHEB(cs14) CHEB(cs15) }
#define RED(CS) { \
    CS.x += __shfl_xor(CS.x, 16); CS.x += __shfl_xor(CS.x, 32); \
    CS.y += __shfl_xor(CS.y, 16); CS.y += __shfl_xor(CS.y, 32); }
#define ST(CS, K) { wred[wc][l15][K] = CS.x; wred[wc][l15][16 + K] = CS.y; }
#define FIN(CS, KK) { \
    constexpr float tk = DT * (float)(KK); \
    const float g  = __expf(-0.5f * tk * tk); \
    const float w  = (((KK) == 16) ? DT : 2.0f * DT) * g; \
    const float totC = wred[wc][l15][(KK) - 1]      + CS.x; \
    const float totS = wred[wc][l15][16 + (KK) - 1] + CS.y; \
    const float cm = fmaf(totC, invB, -g); \
    const float sm = totS * invB; \
    s = fmaf(w, fmaf(cm, cm, sm * sm), s); }

__global__ __launch_bounds__(512) void fused_kernel(const ushort* __restrict__ zb,
                                                    const ushort* __restrict__ ant,
                                                    float* __restrict__ partials) {
    // As (32 KB) unioned with CF-reduce scratch. Total LDS = 48 KB -> 3 blk/CU, 24 waves.
    __shared__ __align__(16) union SharedU {
        ushort As[128 * 128];
        struct { float wred[4][16][33]; float bred[4]; } r;
    } u;
    __shared__ __align__(16) ushort Bs[64 * 128];

    const int tid  = threadIdx.x;
    // XCD-grouped bijection: xcd = bid&7 gets t in {xcd*4 .. xcd*4+3}, all 16 m-blocks.
    const int bid  = blockIdx.x;                    // 0..511
    const int idx  = bid >> 3;                      // 0..63
    const int t    = (bid & 7) * 4 + (idx & 3);
    const int mBi  = idx >> 2;                      // 0..15
    const int mB   = mBi * 64;

    const int wave = tid >> 6;                      // 0..7
    const int lane = tid & 63;
    const int wr   = wave >> 2;                     // 0..1  b-row half
    const int wc   = wave & 3;                      // 0..3  m-col quarter
    const int l15  = lane & 15;
    const int lhi  = lane >> 4;

    const int rofs = lane >> 4;                     // 0..3
    const int gl   = lane & 15;

    const ushort* zrow = zb + (size_t)t * B_DIM * D_DIM;

    f32x4 acc[4];
#pragma unroll
    for (int fm = 0; fm < 4; ++fm) acc[fm] = (f32x4)(0.0f);

#pragma unroll
    for (int it = 0; it < 4; ++it) {
        const int k0 = it * 128;
        // stage A: 32 gload16 (4/wave); B: 16 gload16 (2/wave); source pre-swizzled
#pragma unroll
        for (int j = 0; j < 4; ++j) {
            const int r0  = wave * 16 + j * 4;
            const int row = r0 + rofs;
            const int gs  = gl ^ (row & 15);
            gload16(&zrow[(size_t)row * D_DIM + k0 + gs * 8], &u.As[r0 * 128]);
        }
#pragma unroll
        for (int j = 0; j < 2; ++j) {
            const int r0  = wave * 8 + j * 4;
            const int row = r0 + rofs;
            const int gs  = gl ^ (row & 15);
            gload16(&ant[(size_t)(mB + row) * D_DIM + k0 + gs * 8], &Bs[r0 * 128]);
        }
        __syncthreads();                   // drains vmcnt -> LDS visible

#pragma unroll
        for (int ks = 0; ks < 4; ++ks) {
            const int gd = (ks * 4 + lhi) ^ l15;    // swizzled granule (row&15 == l15)
            const int co = gd * 8;
            const bf16x8 bfrag = *reinterpret_cast<const bf16x8*>(&Bs[(wc * 16 + l15) * 128 + co]);
#pragma unroll
            for (int fm = 0; fm < 4; ++fm) {
                const bf16x8 afrag = *reinterpret_cast<const bf16x8*>(&u.As[(wr * 64 + fm * 16 + l15) * 128 + co]);
                acc[fm] = __builtin_amdgcn_mfma_f32_16x16x32_bf16(afrag, bfrag, acc[fm], 0, 0, 0);
            }
        }
        __syncthreads();                   // readers done before overwrite / union reuse
    }

    float (&wred)[4][16][33] = u.r.wred;   // As region dead past final barrier
    float (&bred)[4] = u.r.bred;

    // ---- CF: per lane m = mB + wc*16 + l15 fixed; 16 b-values in acc (validated) ----
    f32x2 cs0  = {0.f, 0.f}, cs1  = {0.f, 0.f}, cs2  = {0.f, 0.f}, cs3  = {0.f, 0.f};
    f32x2 cs4  = {0.f, 0.f}, cs5  = {0.f, 0.f}, cs6  = {0.f, 0.f}, cs7  = {0.f, 0.f};
    f32x2 cs8  = {0.f, 0.f}, cs9  = {0.f, 0.f}, cs10 = {0.f, 0.f}, cs11 = {0.f, 0.f};
    f32x2 cs12 = {0.f, 0.f}, cs13 = {0.f, 0.f}, cs14 = {0.f, 0.f}, cs15 = {0.f, 0.f};

#pragma unroll
    for (int fm = 0; fm < 4; ++fm) {
        const f32x4 av = acc[fm];
        CF_ALL(av.x) CF_ALL(av.y) CF_ALL(av.z) CF_ALL(av.w)
    }

    RED(cs0)  RED(cs1)  RED(cs2)  RED(cs3)  RED(cs4)  RED(cs5)  RED(cs6)  RED(cs7)
    RED(cs8)  RED(cs9)  RED(cs10) RED(cs11) RED(cs12) RED(cs13) RED(cs14) RED(cs15)

    if (wr == 0 && lane < 16) {            // waves 0..3 (wc = 0..3)
        ST(cs0, 0)   ST(cs1, 1)   ST(cs2, 2)   ST(cs3, 3)
        ST(cs4, 4)   ST(cs5, 5)   ST(cs6, 6)   ST(cs7, 7)
        ST(cs8, 8)   ST(cs9, 9)   ST(cs10, 10) ST(cs11, 11)
        ST(cs12, 12) ST(cs13, 13) ST(cs14, 14) ST(cs15, 15)
    }
    __syncthreads();

    float s = 0.0f;
    if (wr == 1) {                         // waves 4..7 (wc = 0..3)
        const float invB = 1.0f / 128.0f;
        FIN(cs0, 1)   FIN(cs1, 2)   FIN(cs2, 3)   FIN(cs3, 4)
        FIN(cs4, 5)   FIN(cs5, 6)   FIN(cs6, 7)   FIN(cs7, 8)
        FIN(cs8, 9)   FIN(cs9, 10)  FIN(cs10, 11) FIN(cs11, 12)
        FIN(cs12, 13) FIN(cs13, 14) FIN(cs14, 15) FIN(cs15, 16)
        // butterfly over 64 lanes: each l15 column counted 4x (lhi copies)
#pragma unroll
        for (int m = 1; m < 64; m <<= 1) s += __shfl_xor(s, m);
        if (lane == 0) bred[wc] = s;
    }
    __syncthreads();
    // plain uncontended store (R17 win preserved); scale folded into finalize
    if (tid == 0)
        partials[t * 16 + mBi] = bred[0] + bred[1] + bred[2] + bred[3];
}

// ---------- K3: final reduce of 512 partials ----------
// out = sum(partials) * (0.25 dup) * 128 / (T*M) = sum / 1024
__global__ __launch_bounds__(256) void finalize_kernel(const float* __restrict__ partials,
                                                       float* __restrict__ out) {
    __shared__ float red[256];
    const int tid = threadIdx.x;
    red[tid] = partials[tid] + partials[tid + 256];
    __syncthreads();
    for (int s = 128; s > 0; s >>= 1) {
        if (tid < s) red[tid] += red[tid + s];
        __syncthreads();
    }
    if (tid == 0) out[0] = red[0] * (1.0f / 1024.0f);
}

extern "C" void kernel_launch(void* const* d_in, const int* in_sizes, int n_in,
                              void* d_out, int out_size, void* d_ws, size_t ws_size,
                              hipStream_t stream) {
    const float* z = (const float*)d_in[0];   // (32,128,512)
    const float* A = (const float*)d_in[1];   // (512,1024)
    float* out = (float*)d_out;

    char* ws = (char*)d_ws;
    ushort* zb       = (ushort*)ws;                        // 4 MB
    ushort* ant      = (ushort*)(ws + 4 * 1024 * 1024);    // 1 MB
    float*  partials = (float*)(ws + 5 * 1024 * 1024);     // 2 KB

    prep_kernel<<<576, 256, 0, stream>>>(A, z, zb, ant);
    fused_kernel<<<512, 512, 0, stream>>>(zb, ant, partials);
    finalize_kernel<<<1, 256, 0, stream>>>(partials, out);
}